// Round 9
// baseline (164.283 us; speedup 1.0000x reference)
//
#include <hip/hip_runtime.h>
#include <hip/hip_bf16.h>

#define NB 8
#define CH 256
#define NN 4096
#define CQK 32
#define LOG2E 1.4426950408889634f

typedef __attribute__((ext_vector_type(4))) float f32x4;
typedef __attribute__((ext_vector_type(8))) short bf16x8;
typedef unsigned short u16;

// f32 -> bf16 round-to-nearest-even (no NaN inputs here)
static __device__ __forceinline__ u16 f2bf(float f) {
  unsigned int u = __float_as_uint(f);
  unsigned int r = (u + 0x7fffu + ((u >> 16) & 1u)) >> 16;
  return (u16)r;
}

// ---------------------------------------------------------------------------
// Kernel 1: weights -> bf16. Wqk = [Wq*log2e ; Wk] (64 x 256); bqk likewise.
// ---------------------------------------------------------------------------
__global__ void prep_weights(const float* __restrict__ Wq, const float* __restrict__ bq,
                             const float* __restrict__ Wk, const float* __restrict__ bk,
                             const float* __restrict__ Wv,
                             u16* __restrict__ Wqk, u16* __restrict__ Wvb,
                             float* __restrict__ bqk) {
  int i = blockIdx.x * 256 + threadIdx.x;
  if (i < 64 * 256) {
    int o = i >> 8, c = i & 255;
    float w = (o < 32) ? Wq[o * 256 + c] * LOG2E : Wk[(o - 32) * 256 + c];
    Wqk[i] = f2bf(w);
  }
  if (i < 256 * 256) {
    Wvb[i] = f2bf(Wv[i]);
  }
  if (i < 64) bqk[i] = (i < 32) ? bq[i] * LOG2E : bk[i - 32];
}

// ---------------------------------------------------------------------------
// Kernel 2: x [B,C,N] f32 -> xT [B,N,C] bf16  (LDS tile transpose)
// ---------------------------------------------------------------------------
__global__ __launch_bounds__(256) void transpose_x(const float* __restrict__ x,
                                                   u16* __restrict__ xT) {
  __shared__ u16 t[64][66];
  const int n0 = blockIdx.x * 64, c0 = blockIdx.y * 64, b = blockIdx.z;
  const int tid = threadIdx.x;
  const int nl = tid & 63, cl = tid >> 6;
  const float* xp = x + ((size_t)b * CH + c0) * NN + n0;
#pragma unroll
  for (int p = 0; p < 16; ++p) {
    int c = p * 4 + cl;
    t[c][nl] = f2bf(xp[(size_t)c * NN + nl]);
  }
  __syncthreads();
  u16* op = xT + ((size_t)b * NN + n0) * CH + c0;
#pragma unroll
  for (int p = 0; p < 16; ++p) {
    int n = p * 4 + cl;
    op[(size_t)n * CH + nl] = t[nl][n];
  }
}

// ---------------------------------------------------------------------------
// Kernel 3: BOTH projections in one launch (mode by blockIdx.x).
//   bx <  64 : qk proj. rows n = bx*64..; out qbuf/kbuf [B][N][32] packed.
//   bx >= 64 : v proj.  idx = bx-64: ch-tile = (idx&3)*64, m-tile = (idx>>2)*64;
//              out vbuf fragment-native [((b*128+m>>5)*256+ch)*32 + (m&31)].
// ---------------------------------------------------------------------------
__global__ __launch_bounds__(256) void proj_all(
    const u16* __restrict__ xT, const u16* __restrict__ Wqk,
    const u16* __restrict__ Wvb, const float* __restrict__ bqk,
    const float* __restrict__ bv,
    u16* __restrict__ qbuf, u16* __restrict__ kbuf, u16* __restrict__ vbuf) {
  const int b = blockIdx.y;
  const int tid = threadIdx.x, w = tid >> 6, l = tid & 63, g = l >> 4, lr = l & 15;
  const f32x4 fzero = {0.f, 0.f, 0.f, 0.f};

  const int qkmode = (blockIdx.x < 64);
  int m0, c0;
  const u16 *Ap, *Bp;
  if (qkmode) {
    m0 = blockIdx.x * 64;  c0 = 0;
    Ap = xT + (size_t)b * NN * CH + (size_t)(m0 + w * 16 + lr) * 256 + g * 8;
    Bp = Wqk + (size_t)(c0 + lr) * 256 + g * 8;
  } else {
    const int idx = blockIdx.x - 64;
    m0 = (idx & 3) * 64;          // ch rows
    c0 = (idx >> 2) * 64;         // m cols
    Ap = Wvb + (size_t)(m0 + w * 16 + lr) * 256 + g * 8;
    Bp = xT + (size_t)b * NN * CH + (size_t)(c0 + lr) * 256 + g * 8;
  }

  f32x4 acc[4];
#pragma unroll
  for (int ct = 0; ct < 4; ++ct) acc[ct] = fzero;

#pragma unroll
  for (int kk = 0; kk < 8; ++kk) {
    bf16x8 af = *(const bf16x8*)(Ap + kk * 32);
#pragma unroll
    for (int ct = 0; ct < 4; ++ct) {
      bf16x8 bf = *(const bf16x8*)(Bp + (size_t)ct * 16 * 256 + kk * 32);
      acc[ct] = __builtin_amdgcn_mfma_f32_16x16x32_bf16(af, bf, acc[ct], 0, 0, 0);
    }
  }

  if (qkmode) {
#pragma unroll
    for (int ct = 0; ct < 4; ++ct) {
      int col = ct * 16 + lr;
      float bc = bqk[col];
#pragma unroll
      for (int r = 0; r < 4; ++r) {
        int row = m0 + w * 16 + g * 4 + r;  // n
        u16 h = f2bf(acc[ct][r] + bc);
        if (col < 32) qbuf[((size_t)(b * NN + row)) * 32 + col] = h;
        else          kbuf[((size_t)(b * NN + row)) * 32 + (col - 32)] = h;
      }
    }
  } else {
#pragma unroll
    for (int ct = 0; ct < 4; ++ct) {
      int col = c0 + ct * 16 + lr;  // m
#pragma unroll
      for (int r = 0; r < 4; ++r) {
        int row = m0 + w * 16 + g * 4 + r;  // ch
        u16 h = f2bf(acc[ct][r] + bv[row]);
        vbuf[((size_t)(b * 128 + (col >> 5)) * 256 + row) * 32 + (col & 31)] = h;
      }
    }
  }
}

// ---------------------------------------------------------------------------
// Kernel 4: fused attention, 4 waves / 256 threads (halves P-LDS traffic per
// query: every wave reads the whole 8KB P tile, so fewer waves per block =
// less redundancy). Wave w: QK^T+softmax for its OWN 16-query tile (full
// 64-m column -> complete per-row lsum in-wave), PV for 64 channels.
// Software-pipelined across the barrier as in round 8; setprio around the
// PV MFMA cluster (T5). All global loads lane-contiguous 1KB.
// ---------------------------------------------------------------------------
#define KLOAD(t, sub) (*(const bf16x8*)(kp + (size_t)((((t) & 63) * 64) + (sub) * 16) * 32))
#define VLOAD(s, c) (*(const bf16x8*)(vp + (size_t)((s) & 127) * 8192 + (c) * 512))

#define EXPP(S, PW, MASK) {                                                                   \
  float e0 = __builtin_amdgcn_exp2f(S[0]);                                                    \
  float e1 = __builtin_amdgcn_exp2f(S[1]);                                                    \
  float e2 = __builtin_amdgcn_exp2f(S[2]);                                                    \
  float e3 = __builtin_amdgcn_exp2f(S[3]);                                                    \
  lsum += (MASK) * ((e0 + e1) + (e2 + e3));                                                   \
  PW.x = __builtin_amdgcn_perm(__float_as_uint(e1) + 0x8000u, __float_as_uint(e0) + 0x8000u, 0x07060302u); \
  PW.y = __builtin_amdgcn_perm(__float_as_uint(e3) + 0x8000u, __float_as_uint(e2) + 0x8000u, 0x07060302u); \
}

#define PBAR() do {                                  \
  __builtin_amdgcn_sched_barrier(0);                 \
  asm volatile("s_waitcnt lgkmcnt(0)");              \
  __builtin_amdgcn_s_barrier();                      \
  __builtin_amdgcn_sched_barrier(0);                 \
} while (0)

// post-barrier: read P(t) from Pb[BUF], write P(t+1) (pw0..3) -> Pb[BUF^1],
// 32 PV MFMA with V regs V0..V7 (ct-major 0..3 = m-half 0, 4..7 = half 1).
#define PVPHASE(BUF, V0, V1, V2, V3, V4, V5, V6, V7) {                                        \
  const char* prb = (const char*)Pb + (BUF) * 8192;                                           \
  bf16x8 pa0[4], pa1[4];                                                                      \
  _Pragma("unroll")                                                                           \
  for (int nt = 0; nt < 4; ++nt) {                                                            \
    const int row = nt * 16 + lr;                                                             \
    const int rswz = (row & 7) << 4;                                                          \
    pa0[nt] = *(const bf16x8*)(prb + row * 128 + ((g * 16) ^ rswz));                          \
    pa1[nt] = *(const bf16x8*)(prb + row * 128 + ((64 + g * 16) ^ rswz));                     \
  }                                                                                           \
  char* pdst = (char*)Pb + ((BUF) ^ 1) * 8192 + prow * 128;                                   \
  *(uint2*)(pdst + ((0 * 32 + g * 8) ^ wswz)) = pw0;                                          \
  *(uint2*)(pdst + ((1 * 32 + g * 8) ^ wswz)) = pw1;                                          \
  *(uint2*)(pdst + ((2 * 32 + g * 8) ^ wswz)) = pw2;                                          \
  *(uint2*)(pdst + ((3 * 32 + g * 8) ^ wswz)) = pw3;                                          \
  __builtin_amdgcn_s_setprio(1);                                                              \
  _Pragma("unroll")                                                                           \
  for (int nt = 0; nt < 4; ++nt) {                                                            \
    oacc[nt][0] = __builtin_amdgcn_mfma_f32_16x16x32_bf16(V0, pa0[nt], oacc[nt][0], 0, 0, 0); \
    oacc[nt][1] = __builtin_amdgcn_mfma_f32_16x16x32_bf16(V1, pa0[nt], oacc[nt][1], 0, 0, 0); \
    oacc[nt][2] = __builtin_amdgcn_mfma_f32_16x16x32_bf16(V2, pa0[nt], oacc[nt][2], 0, 0, 0); \
    oacc[nt][3] = __builtin_amdgcn_mfma_f32_16x16x32_bf16(V3, pa0[nt], oacc[nt][3], 0, 0, 0); \
    oacc[nt][0] = __builtin_amdgcn_mfma_f32_16x16x32_bf16(V4, pa1[nt], oacc[nt][0], 0, 0, 0); \
    oacc[nt][1] = __builtin_amdgcn_mfma_f32_16x16x32_bf16(V5, pa1[nt], oacc[nt][1], 0, 0, 0); \
    oacc[nt][2] = __builtin_amdgcn_mfma_f32_16x16x32_bf16(V6, pa1[nt], oacc[nt][2], 0, 0, 0); \
    oacc[nt][3] = __builtin_amdgcn_mfma_f32_16x16x32_bf16(V7, pa1[nt], oacc[nt][3], 0, 0, 0); \
  }                                                                                           \
  __builtin_amdgcn_s_setprio(0);                                                              \
}

__global__ __launch_bounds__(256, 2) void attn_fused(
    const u16* __restrict__ qb, const u16* __restrict__ kbuf,
    const u16* __restrict__ vbuf, const float* __restrict__ x,
    const float* __restrict__ gamma_p, float* __restrict__ out) {
  __shared__ __align__(128) char Pb[2][64 * 128];
  __shared__ float lpart[4][16];

  const int b = blockIdx.x;          // %8 of linear id -> XCD pinning
  const int n0 = blockIdx.y * 64;
  const int tid = threadIdx.x, w = tid >> 6, l = tid & 63, g = l >> 4, lr = l & 15;
  const float gamma0 = gamma_p[0];
  const f32x4 fzero = {0.f, 0.f, 0.f, 0.f};

  // q fragment (B-operand) for this wave's own 16-query tile
  bf16x8 qf = *(const bf16x8*)(qb + ((size_t)b * NN + n0 + w * 16 + lr) * 32 + g * 8);

  const u16* kp = kbuf + (size_t)b * (NN * 32) + (size_t)lr * 32 + g * 8;
  const u16* vp = vbuf + (size_t)b * 1048576 + (size_t)(w * 64 + lr) * 32 + g * 8;

  f32x4 oacc[4][4];
#pragma unroll
  for (int nt = 0; nt < 4; ++nt)
#pragma unroll
    for (int ct = 0; ct < 4; ++ct) oacc[nt][ct] = fzero;
  float lsum = 0.f;

  const int prow = w * 16 + lr;
  const int wswz = (prow & 7) << 4;

  // ---- prologue: prepare tile 0 into Pb[0]; prefetch V(0), K(1) ----
  bf16x8 kA0 = KLOAD(0, 0), kA1 = KLOAD(0, 1), kA2 = KLOAD(0, 2), kA3 = KLOAD(0, 3);
  bf16x8 vA0 = VLOAD(0, 0), vA1 = VLOAD(0, 1), vA2 = VLOAD(0, 2), vA3 = VLOAD(0, 3);
  bf16x8 vA4 = VLOAD(1, 0), vA5 = VLOAD(1, 1), vA6 = VLOAD(1, 2), vA7 = VLOAD(1, 3);
  bf16x8 kB0 = KLOAD(1, 0), kB1 = KLOAD(1, 1), kB2 = KLOAD(1, 2), kB3 = KLOAD(1, 3);
  bf16x8 vB0, vB1, vB2, vB3, vB4, vB5, vB6, vB7;
  uint2 pw0, pw1, pw2, pw3;
  {
    f32x4 s0 = __builtin_amdgcn_mfma_f32_16x16x32_bf16(kA0, qf, fzero, 0, 0, 0);
    f32x4 s1 = __builtin_amdgcn_mfma_f32_16x16x32_bf16(kA1, qf, fzero, 0, 0, 0);
    f32x4 s2 = __builtin_amdgcn_mfma_f32_16x16x32_bf16(kA2, qf, fzero, 0, 0, 0);
    f32x4 s3 = __builtin_amdgcn_mfma_f32_16x16x32_bf16(kA3, qf, fzero, 0, 0, 0);
    EXPP(s0, pw0, 1.0f); EXPP(s1, pw1, 1.0f); EXPP(s2, pw2, 1.0f); EXPP(s3, pw3, 1.0f);
    char* pdst = (char*)Pb + prow * 128;
    *(uint2*)(pdst + ((0 * 32 + g * 8) ^ wswz)) = pw0;
    *(uint2*)(pdst + ((1 * 32 + g * 8) ^ wswz)) = pw1;
    *(uint2*)(pdst + ((2 * 32 + g * 8) ^ wswz)) = pw2;
    *(uint2*)(pdst + ((3 * 32 + g * 8) ^ wswz)) = pw3;
  }

  for (int it2 = 0; it2 < 32; ++it2) {
    // ============ phase even: consume tile 2*it2; prepare 2*it2+1 ============
    {
      const int tn = 2 * it2 + 1;
      f32x4 s0 = __builtin_amdgcn_mfma_f32_16x16x32_bf16(kB0, qf, fzero, 0, 0, 0);
      f32x4 s1 = __builtin_amdgcn_mfma_f32_16x16x32_bf16(kB1, qf, fzero, 0, 0, 0);
      f32x4 s2 = __builtin_amdgcn_mfma_f32_16x16x32_bf16(kB2, qf, fzero, 0, 0, 0);
      f32x4 s3 = __builtin_amdgcn_mfma_f32_16x16x32_bf16(kB3, qf, fzero, 0, 0, 0);
      kA0 = KLOAD(tn + 1, 0); kA1 = KLOAD(tn + 1, 1); kA2 = KLOAD(tn + 1, 2); kA3 = KLOAD(tn + 1, 3);
      vB0 = VLOAD(2 * tn, 0); vB1 = VLOAD(2 * tn, 1); vB2 = VLOAD(2 * tn, 2); vB3 = VLOAD(2 * tn, 3);
      vB4 = VLOAD(2 * tn + 1, 0); vB5 = VLOAD(2 * tn + 1, 1); vB6 = VLOAD(2 * tn + 1, 2); vB7 = VLOAD(2 * tn + 1, 3);
      EXPP(s0, pw0, 1.0f); EXPP(s1, pw1, 1.0f); EXPP(s2, pw2, 1.0f); EXPP(s3, pw3, 1.0f);
      PBAR();
      PVPHASE(0, vA0, vA1, vA2, vA3, vA4, vA5, vA6, vA7);
    }
    // ============ phase odd: consume 2*it2+1; prepare 2*it2+2 ============
    {
      const int tn = 2 * it2 + 2;
      const float tmask = (it2 < 31) ? 1.0f : 0.0f;  // exclude wrapped tile 64
      f32x4 s0 = __builtin_amdgcn_mfma_f32_16x16x32_bf16(kA0, qf, fzero, 0, 0, 0);
      f32x4 s1 = __builtin_amdgcn_mfma_f32_16x16x32_bf16(kA1, qf, fzero, 0, 0, 0);
      f32x4 s2 = __builtin_amdgcn_mfma_f32_16x16x32_bf16(kA2, qf, fzero, 0, 0, 0);
      f32x4 s3 = __builtin_amdgcn_mfma_f32_16x16x32_bf16(kA3, qf, fzero, 0, 0, 0);
      kB0 = KLOAD(tn + 1, 0); kB1 = KLOAD(tn + 1, 1); kB2 = KLOAD(tn + 1, 2); kB3 = KLOAD(tn + 1, 3);
      vA0 = VLOAD(2 * tn, 0); vA1 = VLOAD(2 * tn, 1); vA2 = VLOAD(2 * tn, 2); vA3 = VLOAD(2 * tn, 3);
      vA4 = VLOAD(2 * tn + 1, 0); vA5 = VLOAD(2 * tn + 1, 1); vA6 = VLOAD(2 * tn + 1, 2); vA7 = VLOAD(2 * tn + 1, 3);
      EXPP(s0, pw0, tmask); EXPP(s1, pw1, tmask); EXPP(s2, pw2, tmask); EXPP(s3, pw3, tmask);
      PBAR();
      PVPHASE(1, vB0, vB1, vB2, vB3, vB4, vB5, vB6, vB7);
    }
  }

  // ---- epilogue: lsum complete per wave; share across waves, write out ----
  lsum += __shfl_xor(lsum, 16);
  lsum += __shfl_xor(lsum, 32);
  if (l < 16) lpart[w][lr] = lsum;
  __syncthreads();

  const size_t bbase = (size_t)b * CH * NN;
#pragma unroll
  for (int nt = 0; nt < 4; ++nt) {
    const float linv = 1.f / lpart[nt][lr];
    const int ncol = n0 + nt * 16 + lr;
#pragma unroll
    for (int ct = 0; ct < 4; ++ct) {
      const int cbase = w * 64 + ct * 16 + g * 4;
#pragma unroll
      for (int r = 0; r < 4; ++r) {
        const size_t off = bbase + (size_t)(cbase + r) * NN + ncol;
        out[off] = gamma0 * (oacc[nt][ct][r] * linv) + x[off];
      }
    }
  }
}

// ---------------------------------------------------------------------------
extern "C" void kernel_launch(void* const* d_in, const int* in_sizes, int n_in,
                              void* d_out, int out_size, void* d_ws, size_t ws_size,
                              hipStream_t stream) {
  const float* x     = (const float*)d_in[0];
  const float* Wq    = (const float*)d_in[1];
  const float* bq    = (const float*)d_in[2];
  const float* Wk    = (const float*)d_in[3];
  const float* bk    = (const float*)d_in[4];
  const float* Wv    = (const float*)d_in[5];
  const float* bv    = (const float*)d_in[6];
  const float* gamma = (const float*)d_in[7];
  float* out = (float*)d_out;

  char* ws = (char*)d_ws;
  u16*   xT   = (u16*)(ws);                 // [B,N,C] bf16        16,777,216 B
  u16*   qbuf = (u16*)(ws + 16777216);      // [B,N,32] packed      2,097,152 B
  u16*   kbuf = (u16*)(ws + 18874368);      // [B,N,32] packed      2,097,152 B
  u16*   vbuf = (u16*)(ws + 20971520);      // v fragments         16,777,216 B
  u16*   Wqk  = (u16*)(ws + 37748736);      // [64,256] bf16           32,768 B
  u16*   Wvb  = (u16*)(ws + 37781504);      // [256,256] bf16         131,072 B
  float* bqk  = (float*)(ws + 37912576);    // [64] f32                   256 B

  prep_weights<<<256, 256, 0, stream>>>(Wq, bq, Wk, bk, Wv, Wqk, Wvb, bqk);
  transpose_x<<<dim3(64, 4, 8), 256, 0, stream>>>(x, xT);
  proj_all<<<dim3(320, 8), 256, 0, stream>>>(xT, Wqk, Wvb, bqk, bv, qbuf, kbuf, vbuf);
  attn_fused<<<dim3(8, 64), 256, 0, stream>>>(qbuf, kbuf, vbuf, x, gamma, out);
}

// Round 10
// 144.645 us; speedup vs baseline: 1.1358x; 1.1358x over previous
//
#include <hip/hip_runtime.h>
#include <hip/hip_bf16.h>

#define NB 8
#define CH 256
#define NN 4096
#define CQK 32
#define LOG2E 1.4426950408889634f

typedef __attribute__((ext_vector_type(4))) float f32x4;
typedef __attribute__((ext_vector_type(8))) short bf16x8;
typedef unsigned short u16;

// f32 -> bf16 round-to-nearest-even (no NaN inputs here)
static __device__ __forceinline__ u16 f2bf(float f) {
  unsigned int u = __float_as_uint(f);
  unsigned int r = (u + 0x7fffu + ((u >> 16) & 1u)) >> 16;
  return (u16)r;
}

// ---------------------------------------------------------------------------
// Kernel 1: weights -> bf16. Wqk = [Wq*log2e ; Wk] (64 x 256); bqk likewise.
// ---------------------------------------------------------------------------
__global__ void prep_weights(const float* __restrict__ Wq, const float* __restrict__ bq,
                             const float* __restrict__ Wk, const float* __restrict__ bk,
                             const float* __restrict__ Wv,
                             u16* __restrict__ Wqk, u16* __restrict__ Wvb,
                             float* __restrict__ bqk) {
  int i = blockIdx.x * 256 + threadIdx.x;
  if (i < 64 * 256) {
    int o = i >> 8, c = i & 255;
    float w = (o < 32) ? Wq[o * 256 + c] * LOG2E : Wk[(o - 32) * 256 + c];
    Wqk[i] = f2bf(w);
  }
  if (i < 256 * 256) {
    Wvb[i] = f2bf(Wv[i]);
  }
  if (i < 64) bqk[i] = (i < 32) ? bq[i] * LOG2E : bk[i - 32];
}

// ---------------------------------------------------------------------------
// Kernel 2: x [B,C,N] f32 -> xT [B,N,C] bf16  (LDS tile transpose)
// ---------------------------------------------------------------------------
__global__ __launch_bounds__(256) void transpose_x(const float* __restrict__ x,
                                                   u16* __restrict__ xT) {
  __shared__ u16 t[64][66];
  const int n0 = blockIdx.x * 64, c0 = blockIdx.y * 64, b = blockIdx.z;
  const int tid = threadIdx.x;
  const int nl = tid & 63, cl = tid >> 6;
  const float* xp = x + ((size_t)b * CH + c0) * NN + n0;
#pragma unroll
  for (int p = 0; p < 16; ++p) {
    int c = p * 4 + cl;
    t[c][nl] = f2bf(xp[(size_t)c * NN + nl]);
  }
  __syncthreads();
  u16* op = xT + ((size_t)b * NN + n0) * CH + c0;
#pragma unroll
  for (int p = 0; p < 16; ++p) {
    int n = p * 4 + cl;
    op[(size_t)n * CH + nl] = t[nl][n];
  }
}

// ---------------------------------------------------------------------------
// Kernel 3: BOTH projections in one launch (mode by blockIdx.x).
// ---------------------------------------------------------------------------
__global__ __launch_bounds__(256) void proj_all(
    const u16* __restrict__ xT, const u16* __restrict__ Wqk,
    const u16* __restrict__ Wvb, const float* __restrict__ bqk,
    const float* __restrict__ bv,
    u16* __restrict__ qbuf, u16* __restrict__ kbuf, u16* __restrict__ vbuf) {
  const int b = blockIdx.y;
  const int tid = threadIdx.x, w = tid >> 6, l = tid & 63, g = l >> 4, lr = l & 15;
  const f32x4 fzero = {0.f, 0.f, 0.f, 0.f};

  const int qkmode = (blockIdx.x < 64);
  int m0, c0;
  const u16 *Ap, *Bp;
  if (qkmode) {
    m0 = blockIdx.x * 64;  c0 = 0;
    Ap = xT + (size_t)b * NN * CH + (size_t)(m0 + w * 16 + lr) * 256 + g * 8;
    Bp = Wqk + (size_t)(c0 + lr) * 256 + g * 8;
  } else {
    const int idx = blockIdx.x - 64;
    m0 = (idx & 3) * 64;          // ch rows
    c0 = (idx >> 2) * 64;         // m cols
    Ap = Wvb + (size_t)(m0 + w * 16 + lr) * 256 + g * 8;
    Bp = xT + (size_t)b * NN * CH + (size_t)(c0 + lr) * 256 + g * 8;
  }

  f32x4 acc[4];
#pragma unroll
  for (int ct = 0; ct < 4; ++ct) acc[ct] = fzero;

#pragma unroll
  for (int kk = 0; kk < 8; ++kk) {
    bf16x8 af = *(const bf16x8*)(Ap + kk * 32);
#pragma unroll
    for (int ct = 0; ct < 4; ++ct) {
      bf16x8 bf = *(const bf16x8*)(Bp + (size_t)ct * 16 * 256 + kk * 32);
      acc[ct] = __builtin_amdgcn_mfma_f32_16x16x32_bf16(af, bf, acc[ct], 0, 0, 0);
    }
  }

  if (qkmode) {
#pragma unroll
    for (int ct = 0; ct < 4; ++ct) {
      int col = ct * 16 + lr;
      float bc = bqk[col];
#pragma unroll
      for (int r = 0; r < 4; ++r) {
        int row = m0 + w * 16 + g * 4 + r;  // n
        u16 h = f2bf(acc[ct][r] + bc);
        if (col < 32) qbuf[((size_t)(b * NN + row)) * 32 + col] = h;
        else          kbuf[((size_t)(b * NN + row)) * 32 + (col - 32)] = h;
      }
    }
  } else {
#pragma unroll
    for (int ct = 0; ct < 4; ++ct) {
      int col = c0 + ct * 16 + lr;  // m
#pragma unroll
      for (int r = 0; r < 4; ++r) {
        int row = m0 + w * 16 + g * 4 + r;  // ch
        u16 h = f2bf(acc[ct][r] + bv[row]);
        vbuf[((size_t)(b * 128 + (col >> 5)) * 256 + row) * 32 + (col & 31)] = h;
      }
    }
  }
}

// ---------------------------------------------------------------------------
// Kernel 4: fused attention, 128-QUERY blocks, 8 waves / 512 threads.
// Halves per-query V+K global traffic vs 64-query blocks (the remaining
// structural redundancy: each block streams its batch's whole V).
//   Wave w: QK^T+softmax for its OWN 16-query tile (4 MFMA + 16 exp, full
//   64-m column -> complete in-wave lsum), PV for 32 channels x 128 queries
//   (32 MFMA). MFMA becomes the critical path (~1400 cyc/CU-iter vs
//   LDS ~1125, global ~640, VALU ~400).
// Software-pipelined P across the barrier (r8 structure); setprio on PV.
// Grid dim3(8,32): batch -> XCD pinning; 256 blocks = 1/CU.
// ---------------------------------------------------------------------------
#define KLOAD(t, sub) (*(const bf16x8*)(kp + (size_t)((((t) & 63) * 64) + (sub) * 16) * 32))
#define VLOAD(s, c) (*(const bf16x8*)(vp + (size_t)((s) & 127) * 8192 + (c) * 512))

#define EXPP(S, PW, MASK) {                                                                   \
  float e0 = __builtin_amdgcn_exp2f(S[0]);                                                    \
  float e1 = __builtin_amdgcn_exp2f(S[1]);                                                    \
  float e2 = __builtin_amdgcn_exp2f(S[2]);                                                    \
  float e3 = __builtin_amdgcn_exp2f(S[3]);                                                    \
  lsum += (MASK) * ((e0 + e1) + (e2 + e3));                                                   \
  PW.x = __builtin_amdgcn_perm(__float_as_uint(e1) + 0x8000u, __float_as_uint(e0) + 0x8000u, 0x07060302u); \
  PW.y = __builtin_amdgcn_perm(__float_as_uint(e3) + 0x8000u, __float_as_uint(e2) + 0x8000u, 0x07060302u); \
}

#define PBAR() do {                                  \
  __builtin_amdgcn_sched_barrier(0);                 \
  asm volatile("s_waitcnt lgkmcnt(0)");              \
  __builtin_amdgcn_s_barrier();                      \
  __builtin_amdgcn_sched_barrier(0);                 \
} while (0)

// post-barrier: read P(t) (128 rows) from Pb[BUF], write P(t+1) -> Pb[BUF^1],
// 32 PV MFMA. V0/V1 = m-half 0 (ch grp 0/1), V2/V3 = m-half 1.
#define PVPHASE(BUF, V0, V1, V2, V3) {                                                        \
  const char* prb = (const char*)Pb + (BUF) * 16384;                                          \
  char* pdst = (char*)Pb + ((BUF) ^ 1) * 16384 + prow * 128;                                  \
  *(uint2*)(pdst + ((0 * 32 + g * 8) ^ wswz)) = pw0;                                          \
  *(uint2*)(pdst + ((1 * 32 + g * 8) ^ wswz)) = pw1;                                          \
  *(uint2*)(pdst + ((2 * 32 + g * 8) ^ wswz)) = pw2;                                          \
  *(uint2*)(pdst + ((3 * 32 + g * 8) ^ wswz)) = pw3;                                          \
  __builtin_amdgcn_s_setprio(1);                                                              \
  _Pragma("unroll")                                                                           \
  for (int nt = 0; nt < 8; ++nt) {                                                            \
    const int row = nt * 16 + lr;                                                             \
    const int rswz = (row & 7) << 4;                                                          \
    bf16x8 pa0 = *(const bf16x8*)(prb + row * 128 + ((g * 16) ^ rswz));                       \
    bf16x8 pa1 = *(const bf16x8*)(prb + row * 128 + ((64 + g * 16) ^ rswz));                  \
    oacc[nt][0] = __builtin_amdgcn_mfma_f32_16x16x32_bf16(V0, pa0, oacc[nt][0], 0, 0, 0);     \
    oacc[nt][1] = __builtin_amdgcn_mfma_f32_16x16x32_bf16(V1, pa0, oacc[nt][1], 0, 0, 0);     \
    oacc[nt][0] = __builtin_amdgcn_mfma_f32_16x16x32_bf16(V2, pa1, oacc[nt][0], 0, 0, 0);     \
    oacc[nt][1] = __builtin_amdgcn_mfma_f32_16x16x32_bf16(V3, pa1, oacc[nt][1], 0, 0, 0);     \
  }                                                                                           \
  __builtin_amdgcn_s_setprio(0);                                                              \
}

__global__ __launch_bounds__(512, 2) void attn_fused(
    const u16* __restrict__ qb, const u16* __restrict__ kbuf,
    const u16* __restrict__ vbuf, const float* __restrict__ x,
    const float* __restrict__ gamma_p, float* __restrict__ out) {
  __shared__ __align__(128) char Pb[2][128 * 128];
  __shared__ float lpart[8][16];

  const int b = blockIdx.x;          // %8 of linear id -> XCD pinning
  const int n0 = blockIdx.y * 128;
  const int tid = threadIdx.x, w = tid >> 6, l = tid & 63, g = l >> 4, lr = l & 15;
  const float gamma0 = gamma_p[0];
  const f32x4 fzero = {0.f, 0.f, 0.f, 0.f};

  // q fragment (B-operand) for this wave's own 16-query tile
  bf16x8 qf = *(const bf16x8*)(qb + ((size_t)b * NN + n0 + w * 16 + lr) * 32 + g * 8);

  const u16* kp = kbuf + (size_t)b * (NN * 32) + (size_t)lr * 32 + g * 8;
  const u16* vp = vbuf + (size_t)b * 1048576 + (size_t)(w * 32 + lr) * 32 + g * 8;

  f32x4 oacc[8][2];
#pragma unroll
  for (int nt = 0; nt < 8; ++nt)
#pragma unroll
    for (int ct = 0; ct < 2; ++ct) oacc[nt][ct] = fzero;
  float lsum = 0.f;

  const int prow = w * 16 + lr;
  const int wswz = (prow & 7) << 4;

  // ---- prologue: prepare tile 0 into Pb[0]; prefetch V(0), K(1) ----
  bf16x8 kA0 = KLOAD(0, 0), kA1 = KLOAD(0, 1), kA2 = KLOAD(0, 2), kA3 = KLOAD(0, 3);
  bf16x8 vA0 = VLOAD(0, 0), vA1 = VLOAD(0, 1), vA2 = VLOAD(1, 0), vA3 = VLOAD(1, 1);
  bf16x8 kB0 = KLOAD(1, 0), kB1 = KLOAD(1, 1), kB2 = KLOAD(1, 2), kB3 = KLOAD(1, 3);
  bf16x8 vB0, vB1, vB2, vB3;
  uint2 pw0, pw1, pw2, pw3;
  {
    f32x4 s0 = __builtin_amdgcn_mfma_f32_16x16x32_bf16(kA0, qf, fzero, 0, 0, 0);
    f32x4 s1 = __builtin_amdgcn_mfma_f32_16x16x32_bf16(kA1, qf, fzero, 0, 0, 0);
    f32x4 s2 = __builtin_amdgcn_mfma_f32_16x16x32_bf16(kA2, qf, fzero, 0, 0, 0);
    f32x4 s3 = __builtin_amdgcn_mfma_f32_16x16x32_bf16(kA3, qf, fzero, 0, 0, 0);
    EXPP(s0, pw0, 1.0f); EXPP(s1, pw1, 1.0f); EXPP(s2, pw2, 1.0f); EXPP(s3, pw3, 1.0f);
    char* pdst = (char*)Pb + prow * 128;
    *(uint2*)(pdst + ((0 * 32 + g * 8) ^ wswz)) = pw0;
    *(uint2*)(pdst + ((1 * 32 + g * 8) ^ wswz)) = pw1;
    *(uint2*)(pdst + ((2 * 32 + g * 8) ^ wswz)) = pw2;
    *(uint2*)(pdst + ((3 * 32 + g * 8) ^ wswz)) = pw3;
  }

  for (int it2 = 0; it2 < 32; ++it2) {
    // ============ phase even: consume tile 2*it2; prepare 2*it2+1 ============
    {
      const int tn = 2 * it2 + 1;
      f32x4 s0 = __builtin_amdgcn_mfma_f32_16x16x32_bf16(kB0, qf, fzero, 0, 0, 0);
      f32x4 s1 = __builtin_amdgcn_mfma_f32_16x16x32_bf16(kB1, qf, fzero, 0, 0, 0);
      f32x4 s2 = __builtin_amdgcn_mfma_f32_16x16x32_bf16(kB2, qf, fzero, 0, 0, 0);
      f32x4 s3 = __builtin_amdgcn_mfma_f32_16x16x32_bf16(kB3, qf, fzero, 0, 0, 0);
      kA0 = KLOAD(tn + 1, 0); kA1 = KLOAD(tn + 1, 1); kA2 = KLOAD(tn + 1, 2); kA3 = KLOAD(tn + 1, 3);
      vB0 = VLOAD(2 * tn, 0); vB1 = VLOAD(2 * tn, 1);
      vB2 = VLOAD(2 * tn + 1, 0); vB3 = VLOAD(2 * tn + 1, 1);
      EXPP(s0, pw0, 1.0f); EXPP(s1, pw1, 1.0f); EXPP(s2, pw2, 1.0f); EXPP(s3, pw3, 1.0f);
      PBAR();
      PVPHASE(0, vA0, vA1, vA2, vA3);
    }
    // ============ phase odd: consume 2*it2+1; prepare 2*it2+2 ============
    {
      const int tn = 2 * it2 + 2;
      const float tmask = (it2 < 31) ? 1.0f : 0.0f;  // exclude wrapped tile 64
      f32x4 s0 = __builtin_amdgcn_mfma_f32_16x16x32_bf16(kA0, qf, fzero, 0, 0, 0);
      f32x4 s1 = __builtin_amdgcn_mfma_f32_16x16x32_bf16(kA1, qf, fzero, 0, 0, 0);
      f32x4 s2 = __builtin_amdgcn_mfma_f32_16x16x32_bf16(kA2, qf, fzero, 0, 0, 0);
      f32x4 s3 = __builtin_amdgcn_mfma_f32_16x16x32_bf16(kA3, qf, fzero, 0, 0, 0);
      kB0 = KLOAD(tn + 1, 0); kB1 = KLOAD(tn + 1, 1); kB2 = KLOAD(tn + 1, 2); kB3 = KLOAD(tn + 1, 3);
      vA0 = VLOAD(2 * tn, 0); vA1 = VLOAD(2 * tn, 1);
      vA2 = VLOAD(2 * tn + 1, 0); vA3 = VLOAD(2 * tn + 1, 1);
      EXPP(s0, pw0, tmask); EXPP(s1, pw1, tmask); EXPP(s2, pw2, tmask); EXPP(s3, pw3, tmask);
      PBAR();
      PVPHASE(1, vB0, vB1, vB2, vB3);
    }
  }

  // ---- epilogue: lsum complete per wave; share across waves, write out ----
  lsum += __shfl_xor(lsum, 16);
  lsum += __shfl_xor(lsum, 32);
  if (l < 16) lpart[w][lr] = lsum;
  __syncthreads();

  const size_t bbase = (size_t)b * CH * NN;
#pragma unroll
  for (int nt = 0; nt < 8; ++nt) {
    const float linv = 1.f / lpart[nt][lr];
    const int ncol = n0 + nt * 16 + lr;
#pragma unroll
    for (int ct = 0; ct < 2; ++ct) {
      const int cbase = w * 32 + ct * 16 + g * 4;
#pragma unroll
      for (int r = 0; r < 4; ++r) {
        const size_t off = bbase + (size_t)(cbase + r) * NN + ncol;
        out[off] = gamma0 * (oacc[nt][ct][r] * linv) + x[off];
      }
    }
  }
}

// ---------------------------------------------------------------------------
extern "C" void kernel_launch(void* const* d_in, const int* in_sizes, int n_in,
                              void* d_out, int out_size, void* d_ws, size_t ws_size,
                              hipStream_t stream) {
  const float* x     = (const float*)d_in[0];
  const float* Wq    = (const float*)d_in[1];
  const float* bq    = (const float*)d_in[2];
  const float* Wk    = (const float*)d_in[3];
  const float* bk    = (const float*)d_in[4];
  const float* Wv    = (const float*)d_in[5];
  const float* bv    = (const float*)d_in[6];
  const float* gamma = (const float*)d_in[7];
  float* out = (float*)d_out;

  char* ws = (char*)d_ws;
  u16*   xT   = (u16*)(ws);                 // [B,N,C] bf16        16,777,216 B
  u16*   qbuf = (u16*)(ws + 16777216);      // [B,N,32] packed      2,097,152 B
  u16*   kbuf = (u16*)(ws + 18874368);      // [B,N,32] packed      2,097,152 B
  u16*   vbuf = (u16*)(ws + 20971520);      // v fragments         16,777,216 B
  u16*   Wqk  = (u16*)(ws + 37748736);      // [64,256] bf16           32,768 B
  u16*   Wvb  = (u16*)(ws + 37781504);      // [256,256] bf16         131,072 B
  float* bqk  = (float*)(ws + 37912576);    // [64] f32                   256 B

  prep_weights<<<256, 256, 0, stream>>>(Wq, bq, Wk, bk, Wv, Wqk, Wvb, bqk);
  transpose_x<<<dim3(64, 4, 8), 256, 0, stream>>>(x, xT);
  proj_all<<<dim3(320, 8), 256, 0, stream>>>(xT, Wqk, Wvb, bqk, bv, qbuf, kbuf, vbuf);
  attn_fused<<<dim3(8, 32), 512, 0, stream>>>(qbuf, kbuf, vbuf, x, gamma, out);
}

// Round 11
// 115.091 us; speedup vs baseline: 1.4274x; 1.2568x over previous
//
#include <hip/hip_runtime.h>
#include <hip/hip_bf16.h>

#define NB 8
#define CH 256
#define NN 4096
#define CQK 32
#define LOG2E 1.4426950408889634f

typedef __attribute__((ext_vector_type(4))) float f32x4;
typedef __attribute__((ext_vector_type(16))) float f32x16;
typedef __attribute__((ext_vector_type(8))) short bf16x8;
typedef unsigned short u16;

static __device__ __forceinline__ u16 f2bf(float f) {
  unsigned int u = __float_as_uint(f);
  unsigned int r = (u + 0x7fffu + ((u >> 16) & 1u)) >> 16;
  return (u16)r;
}

// ---------------------------------------------------------------------------
// Kernel 1: weights -> bf16, FRAGMENT-PACKED so projection B/A loads are
// contiguous 1KB wave loads.
//   Wqkf[(((o>>4)*8 + kk)*4 + g)*16 + (o&15)]*8 + j   (o = out col 0..63)
//   Wvf  same with o = ch 0..255.
// ---------------------------------------------------------------------------
__global__ void prep_weights(const float* __restrict__ Wq, const float* __restrict__ bq,
                             const float* __restrict__ Wk, const float* __restrict__ bk,
                             const float* __restrict__ Wv,
                             u16* __restrict__ Wqkf, u16* __restrict__ Wvf,
                             float* __restrict__ bqk) {
  int i = blockIdx.x * 256 + threadIdx.x;   // 65536
  int o = i >> 8, c = i & 255;
  int kk = c >> 5, g2 = (c >> 3) & 3, j = c & 7;
  if (o < 64) {
    float wv = (o < 32) ? Wq[o * 256 + c] * LOG2E : Wk[(o - 32) * 256 + c];
    Wqkf[((((o >> 4) * 8 + kk) * 4 + g2) * 16 + (o & 15)) * 8 + j] = f2bf(wv);
  }
  Wvf[((((o >> 4) * 8 + kk) * 4 + g2) * 16 + (o & 15)) * 8 + j] = f2bf(Wv[i]);
  if (i < 64) bqk[i] = (i < 32) ? bq[i] * LOG2E : bk[i - 32];
}

// ---------------------------------------------------------------------------
// Kernel 2: FUSED transpose + both projections. Block = 64 n of one batch.
// Stages x^T tile [64 n][256 c] bf16 in LDS (XOR swizzle byte^=(n&15)<<4),
// then computes qk (64x64) and v (256ch x 64m) with MFMA, fragments from LDS
// + fragment-packed weights. Eliminates the xT global round-trip.
// ---------------------------------------------------------------------------
__global__ __launch_bounds__(256, 2) void fused_proj(
    const float* __restrict__ x, const u16* __restrict__ Wqkf,
    const u16* __restrict__ Wvf, const float* __restrict__ bqk,
    const float* __restrict__ bv,
    u16* __restrict__ qbuf, u16* __restrict__ kbuf, u16* __restrict__ vbuf) {
  __shared__ __align__(128) char xt[64 * 512];  // row n: 256 c * 2B
  const int b = blockIdx.y, n0 = blockIdx.x * 64;
  const int tid = threadIdx.x, w = tid >> 6, l = tid & 63, g = l >> 4, lr = l & 15;
  const f32x4 fzero = {0.f, 0.f, 0.f, 0.f};

  // ---- stage: coalesced f32 reads along n, packed b32 LDS writes ----
  {
    const int nl = l, cl = w;
    const float* xp = x + (size_t)b * CH * NN + n0 + nl;
    char* xrow = xt + nl * 512;
    const int swz = (nl & 15) << 4;
#pragma unroll
    for (int p = 0; p < 32; ++p) {
      const int c = p * 8 + cl * 2;
      float f0 = xp[(size_t)c * NN], f1 = xp[(size_t)(c + 1) * NN];
      unsigned int pk = (unsigned int)f2bf(f0) | ((unsigned int)f2bf(f1) << 16);
      *(unsigned int*)(xrow + ((c * 2) ^ swz)) = pk;
    }
  }
  __syncthreads();

  const int aswz = lr << 4;  // (n&15)<<4 for rows n = {w,mt}*16 + lr

  // ---- qk projection: rows n = w*16+lr, 64 out cols ----
  {
    f32x4 acc[4];
#pragma unroll
    for (int ct = 0; ct < 4; ++ct) acc[ct] = fzero;
#pragma unroll
    for (int kk = 0; kk < 8; ++kk) {
      bf16x8 af = *(const bf16x8*)(xt + (w * 16 + lr) * 512 + ((kk * 64 + g * 16) ^ aswz));
#pragma unroll
      for (int ct = 0; ct < 4; ++ct) {
        bf16x8 bf = *(const bf16x8*)(Wqkf + (size_t)(((ct * 8 + kk) * 4 + g) * 16 + lr) * 8);
        acc[ct] = __builtin_amdgcn_mfma_f32_16x16x32_bf16(af, bf, acc[ct], 0, 0, 0);
      }
    }
#pragma unroll
    for (int ct = 0; ct < 4; ++ct) {
      const int col = ct * 16 + lr;
      const float bc = bqk[col];
#pragma unroll
      for (int r = 0; r < 4; ++r) {
        const int row = n0 + w * 16 + g * 4 + r;
        u16 h = f2bf(acc[ct][r] + bc);
        if (col < 32) qbuf[((size_t)(b * NN + row)) * 32 + col] = h;
        else          kbuf[((size_t)(b * NN + row)) * 32 + (col - 32)] = h;
      }
    }
  }

  // ---- v projection: wave w owns ch 64w..64w+63, all 64 m ----
  {
    f32x4 vacc[4][4];  // [ct_ch][mt]
#pragma unroll
    for (int ct = 0; ct < 4; ++ct)
#pragma unroll
      for (int mt = 0; mt < 4; ++mt) vacc[ct][mt] = fzero;
#pragma unroll
    for (int kk = 0; kk < 8; ++kk) {
      bf16x8 bfm[4];
#pragma unroll
      for (int mt = 0; mt < 4; ++mt)
        bfm[mt] = *(const bf16x8*)(xt + (mt * 16 + lr) * 512 + ((kk * 64 + g * 16) ^ aswz));
#pragma unroll
      for (int ct = 0; ct < 4; ++ct) {
        bf16x8 af = *(const bf16x8*)(Wvf + (size_t)((((w * 4 + ct) * 8 + kk) * 4 + g) * 16 + lr) * 8);
#pragma unroll
        for (int mt = 0; mt < 4; ++mt)
          vacc[ct][mt] = __builtin_amdgcn_mfma_f32_16x16x32_bf16(af, bfm[mt], vacc[ct][mt], 0, 0, 0);
      }
    }
#pragma unroll
    for (int ct = 0; ct < 4; ++ct) {
#pragma unroll
      for (int mt = 0; mt < 4; ++mt) {
        const int m = n0 + mt * 16 + lr;
#pragma unroll
        for (int r = 0; r < 4; ++r) {
          const int ch = w * 64 + ct * 16 + g * 4 + r;
          vbuf[((size_t)(b * 128 + (m >> 5)) * 256 + ch) * 32 + (m & 31)] = f2bf(vacc[ct][mt][r] + bv[ch]);
        }
      }
    }
  }
}

// ---------------------------------------------------------------------------
// Kernel 3: fused attention, 128-query blocks, 8 waves. QK^T 16x16x32 +
// in-register softmax (unchanged); PV with 32x32x16 MFMA: half the
// instructions at the higher-rate shape. Wave w: own 16-q tile for QK/SM,
// 32-ch slice x all 128 q for PV (4 x f32x16 acc). Software-pipelined P
// across the barrier; setprio on PV cluster.
// ---------------------------------------------------------------------------
#define KLOAD(t, sub) (*(const bf16x8*)(kp + (size_t)((((t) & 63) * 64) + (sub) * 16) * 32))
#define VLOAD32(mg, k16) (*(const bf16x8*)(vp32 + (size_t)((mg) & 127) * 8192 + (k16)))

#define EXPP(S, PW, MASK) {                                                                   \
  float e0 = __builtin_amdgcn_exp2f(S[0]);                                                    \
  float e1 = __builtin_amdgcn_exp2f(S[1]);                                                    \
  float e2 = __builtin_amdgcn_exp2f(S[2]);                                                    \
  float e3 = __builtin_amdgcn_exp2f(S[3]);                                                    \
  lsum += (MASK) * ((e0 + e1) + (e2 + e3));                                                   \
  PW.x = __builtin_amdgcn_perm(__float_as_uint(e1) + 0x8000u, __float_as_uint(e0) + 0x8000u, 0x07060302u); \
  PW.y = __builtin_amdgcn_perm(__float_as_uint(e3) + 0x8000u, __float_as_uint(e2) + 0x8000u, 0x07060302u); \
}

#define PBAR() do {                                  \
  __builtin_amdgcn_sched_barrier(0);                 \
  asm volatile("s_waitcnt lgkmcnt(0)");              \
  __builtin_amdgcn_s_barrier();                      \
  __builtin_amdgcn_sched_barrier(0);                 \
} while (0)

// post-barrier: write P(t+1) -> Pb[BUF^1]; 16x 32x32x16 PV MFMA from Pb[BUF]
#define PVPHASE32(BUF, V00, V01, V10, V11) {                                                  \
  const char* prb = (const char*)Pb + (BUF) * 16384;                                          \
  char* pdst = (char*)Pb + ((BUF) ^ 1) * 16384 + prow * 128;                                  \
  *(uint2*)(pdst + ((0 * 32 + g * 8) ^ wswz)) = pw0;                                          \
  *(uint2*)(pdst + ((1 * 32 + g * 8) ^ wswz)) = pw1;                                          \
  *(uint2*)(pdst + ((2 * 32 + g * 8) ^ wswz)) = pw2;                                          \
  *(uint2*)(pdst + ((3 * 32 + g * 8) ^ wswz)) = pw3;                                          \
  __builtin_amdgcn_s_setprio(1);                                                              \
  _Pragma("unroll")                                                                           \
  for (int qt = 0; qt < 4; ++qt) {                                                            \
    const int row = qt * 32 + (l & 31);                                                       \
    const int rs = (row & 7) << 4;                                                            \
    const char* base = prb + row * 128;                                                       \
    bf16x8 p00 = *(const bf16x8*)(base + ((0 + hi16) ^ rs));                                  \
    bf16x8 p01 = *(const bf16x8*)(base + ((32 + hi16) ^ rs));                                 \
    bf16x8 p10 = *(const bf16x8*)(base + ((64 + hi16) ^ rs));                                 \
    bf16x8 p11 = *(const bf16x8*)(base + ((96 + hi16) ^ rs));                                 \
    oacc32[qt] = __builtin_amdgcn_mfma_f32_32x32x16_bf16(V00, p00, oacc32[qt], 0, 0, 0);      \
    oacc32[qt] = __builtin_amdgcn_mfma_f32_32x32x16_bf16(V01, p01, oacc32[qt], 0, 0, 0);      \
    oacc32[qt] = __builtin_amdgcn_mfma_f32_32x32x16_bf16(V10, p10, oacc32[qt], 0, 0, 0);      \
    oacc32[qt] = __builtin_amdgcn_mfma_f32_32x32x16_bf16(V11, p11, oacc32[qt], 0, 0, 0);      \
  }                                                                                           \
  __builtin_amdgcn_s_setprio(0);                                                              \
}

__global__ __launch_bounds__(512, 2) void attn_fused(
    const u16* __restrict__ qb, const u16* __restrict__ kbuf,
    const u16* __restrict__ vbuf, const float* __restrict__ x,
    const float* __restrict__ gamma_p, float* __restrict__ out) {
  __shared__ __align__(128) char Pb[2][128 * 128];
  __shared__ float lsum_s[128];

  const int b = blockIdx.x;          // batch -> XCD pinning
  const int n0 = blockIdx.y * 128;
  const int tid = threadIdx.x, w = tid >> 6, l = tid & 63, g = l >> 4, lr = l & 15;
  const float gamma0 = gamma_p[0];
  const f32x4 fzero = {0.f, 0.f, 0.f, 0.f};
  const int hi16 = (l >> 5) << 4;

  bf16x8 qf = *(const bf16x8*)(qb + ((size_t)b * NN + n0 + w * 16 + lr) * 32 + g * 8);

  const u16* kp = kbuf + (size_t)b * (NN * 32) + (size_t)lr * 32 + g * 8;
  const u16* vp32 = vbuf + (size_t)b * 1048576 + (size_t)(w * 32 + (l & 31)) * 32 + (l >> 5) * 8;

  f32x16 oacc32[4];
#pragma unroll
  for (int qt = 0; qt < 4; ++qt) oacc32[qt] = (f32x16){};
  float lsum = 0.f;

  const int prow = w * 16 + lr;
  const int wswz = (prow & 7) << 4;

  // ---- prologue: prepare tile 0 into Pb[0]; prefetch V(0), K(1) ----
  bf16x8 kA0 = KLOAD(0, 0), kA1 = KLOAD(0, 1), kA2 = KLOAD(0, 2), kA3 = KLOAD(0, 3);
  bf16x8 vA0 = VLOAD32(0, 0), vA1 = VLOAD32(0, 16), vA2 = VLOAD32(1, 0), vA3 = VLOAD32(1, 16);
  bf16x8 kB0 = KLOAD(1, 0), kB1 = KLOAD(1, 1), kB2 = KLOAD(1, 2), kB3 = KLOAD(1, 3);
  bf16x8 vB0, vB1, vB2, vB3;
  uint2 pw0, pw1, pw2, pw3;
  {
    f32x4 s0 = __builtin_amdgcn_mfma_f32_16x16x32_bf16(kA0, qf, fzero, 0, 0, 0);
    f32x4 s1 = __builtin_amdgcn_mfma_f32_16x16x32_bf16(kA1, qf, fzero, 0, 0, 0);
    f32x4 s2 = __builtin_amdgcn_mfma_f32_16x16x32_bf16(kA2, qf, fzero, 0, 0, 0);
    f32x4 s3 = __builtin_amdgcn_mfma_f32_16x16x32_bf16(kA3, qf, fzero, 0, 0, 0);
    EXPP(s0, pw0, 1.0f); EXPP(s1, pw1, 1.0f); EXPP(s2, pw2, 1.0f); EXPP(s3, pw3, 1.0f);
    char* pdst = (char*)Pb + prow * 128;
    *(uint2*)(pdst + ((0 * 32 + g * 8) ^ wswz)) = pw0;
    *(uint2*)(pdst + ((1 * 32 + g * 8) ^ wswz)) = pw1;
    *(uint2*)(pdst + ((2 * 32 + g * 8) ^ wswz)) = pw2;
    *(uint2*)(pdst + ((3 * 32 + g * 8) ^ wswz)) = pw3;
  }

  for (int it2 = 0; it2 < 32; ++it2) {
    // ============ phase even: consume tile 2*it2; prepare 2*it2+1 ============
    {
      const int tn = 2 * it2 + 1;
      f32x4 s0 = __builtin_amdgcn_mfma_f32_16x16x32_bf16(kB0, qf, fzero, 0, 0, 0);
      f32x4 s1 = __builtin_amdgcn_mfma_f32_16x16x32_bf16(kB1, qf, fzero, 0, 0, 0);
      f32x4 s2 = __builtin_amdgcn_mfma_f32_16x16x32_bf16(kB2, qf, fzero, 0, 0, 0);
      f32x4 s3 = __builtin_amdgcn_mfma_f32_16x16x32_bf16(kB3, qf, fzero, 0, 0, 0);
      kA0 = KLOAD(tn + 1, 0); kA1 = KLOAD(tn + 1, 1); kA2 = KLOAD(tn + 1, 2); kA3 = KLOAD(tn + 1, 3);
      vB0 = VLOAD32(2 * tn, 0); vB1 = VLOAD32(2 * tn, 16);
      vB2 = VLOAD32(2 * tn + 1, 0); vB3 = VLOAD32(2 * tn + 1, 16);
      EXPP(s0, pw0, 1.0f); EXPP(s1, pw1, 1.0f); EXPP(s2, pw2, 1.0f); EXPP(s3, pw3, 1.0f);
      PBAR();
      PVPHASE32(0, vA0, vA1, vA2, vA3);
    }
    // ============ phase odd: consume 2*it2+1; prepare 2*it2+2 ============
    {
      const int tn = 2 * it2 + 2;
      const float tmask = (it2 < 31) ? 1.0f : 0.0f;  // exclude wrapped tile 64
      f32x4 s0 = __builtin_amdgcn_mfma_f32_16x16x32_bf16(kA0, qf, fzero, 0, 0, 0);
      f32x4 s1 = __builtin_amdgcn_mfma_f32_16x16x32_bf16(kA1, qf, fzero, 0, 0, 0);
      f32x4 s2 = __builtin_amdgcn_mfma_f32_16x16x32_bf16(kA2, qf, fzero, 0, 0, 0);
      f32x4 s3 = __builtin_amdgcn_mfma_f32_16x16x32_bf16(kA3, qf, fzero, 0, 0, 0);
      kB0 = KLOAD(tn + 1, 0); kB1 = KLOAD(tn + 1, 1); kB2 = KLOAD(tn + 1, 2); kB3 = KLOAD(tn + 1, 3);
      vA0 = VLOAD32(2 * tn, 0); vA1 = VLOAD32(2 * tn, 16);
      vA2 = VLOAD32(2 * tn + 1, 0); vA3 = VLOAD32(2 * tn + 1, 16);
      EXPP(s0, pw0, tmask); EXPP(s1, pw1, tmask); EXPP(s2, pw2, tmask); EXPP(s3, pw3, tmask);
      PBAR();
      PVPHASE32(1, vB0, vB1, vB2, vB3);
    }
  }

  // ---- epilogue: share lsum, normalize, gamma*O + x ----
  lsum += __shfl_xor(lsum, 16);
  lsum += __shfl_xor(lsum, 32);
  if (l < 16) lsum_s[w * 16 + lr] = lsum;
  __syncthreads();

  const size_t bbase = (size_t)b * CH * NN;
#pragma unroll
  for (int qt = 0; qt < 4; ++qt) {
    const int q = qt * 32 + (l & 31);
    const float linv = 1.f / lsum_s[q];
    const int n = n0 + q;
#pragma unroll
    for (int a = 0; a < 4; ++a) {
#pragma unroll
      for (int rr = 0; rr < 4; ++rr) {
        const int ch = w * 32 + rr + a * 8 + 4 * (l >> 5);
        const size_t off = bbase + (size_t)ch * NN + n;
        out[off] = gamma0 * (oacc32[qt][a * 4 + rr] * linv) + x[off];
      }
    }
  }
}

// ---------------------------------------------------------------------------
extern "C" void kernel_launch(void* const* d_in, const int* in_sizes, int n_in,
                              void* d_out, int out_size, void* d_ws, size_t ws_size,
                              hipStream_t stream) {
  const float* x     = (const float*)d_in[0];
  const float* Wq    = (const float*)d_in[1];
  const float* bq    = (const float*)d_in[2];
  const float* Wk    = (const float*)d_in[3];
  const float* bk    = (const float*)d_in[4];
  const float* Wv    = (const float*)d_in[5];
  const float* bv    = (const float*)d_in[6];
  const float* gamma = (const float*)d_in[7];
  float* out = (float*)d_out;

  char* ws = (char*)d_ws;
  u16*   qbuf = (u16*)(ws);                 // [B,N,32] packed      2,097,152 B
  u16*   kbuf = (u16*)(ws + 2097152);       // [B,N,32] packed      2,097,152 B
  u16*   vbuf = (u16*)(ws + 4194304);       // v fragments         16,777,216 B
  u16*   Wqkf = (u16*)(ws + 20971520);      // packed frags            32,768 B
  u16*   Wvf  = (u16*)(ws + 21004288);      // packed frags           131,072 B
  float* bqk  = (float*)(ws + 21135360);    // [64] f32                   256 B

  prep_weights<<<256, 256, 0, stream>>>(Wq, bq, Wk, bk, Wv, Wqkf, Wvf, bqk);
  fused_proj<<<dim3(64, 8), 256, 0, stream>>>(x, Wqkf, Wvf, bqk, bv, qbuf, kbuf, vbuf);
  attn_fused<<<dim3(8, 32), 512, 0, stream>>>(qbuf, kbuf, vbuf, x, gamma, out);
}